// Round 16
// baseline (43.094 us; speedup 1.0000x reference)
//
#include <hip/hip_runtime.h>
#include <stdint.h>

#define D 128
#define LOG2E 1.4426950408889634f
#define LN2 0.6931471805599453f

typedef float f2 __attribute__((ext_vector_type(2)));
typedef float f4 __attribute__((ext_vector_type(4)));

__device__ __forceinline__ uint16_t f2bf(float f) {
  uint32_t u = __float_as_uint(f);
  u += 0x7fffu + ((u >> 16) & 1u);  // RNE
  return (uint16_t)(u >> 16);
}
__device__ __forceinline__ uint32_t pkbf(float a, float b) {
  return (uint32_t)f2bf(a) | ((uint32_t)f2bf(b) << 16);
}
__device__ __forceinline__ f2 unpkbf(uint32_t u) {
  f2 r;
  r.x = __uint_as_float(u << 16);
  r.y = __uint_as_float(u & 0xffff0000u);
  return r;
}
__device__ __forceinline__ float rdlane(float v, int l) {
  return __int_as_float(__builtin_amdgcn_readlane(__float_as_int(v), l));
}
__device__ __forceinline__ float exp2x(float v) {
#if __has_builtin(__builtin_amdgcn_exp2f)
  return __builtin_amdgcn_exp2f(v);
#else
  return exp2f(v);
#endif
}

// ws layout: 3 tables of uint4[32*64] (32KB each): WMU4 | WLS4(x log2e) | W14.
// entry[jb*64+l].c = pack(bf16 M[2l][4jb+c], bf16 M[2l+1][4jb+c]), masked j<row.
#define WS_NEED (size_t)(3 * 2048 * 16)  // 98304

// ================= prep: mask + column-pack into ws =================
__global__ __launch_bounds__(256)
void iaf_prep(const float* __restrict__ W1, const float* __restrict__ Wmu,
              const float* __restrict__ Wls, uint4* __restrict__ ws) {
  const int t = blockIdx.x * 256 + threadIdx.x;
  if (t >= 32 * 64) return;
  const int jb = t >> 6, l = t & 63;
  const int k0 = 2 * l, k1 = 2 * l + 1;
  uint32_t mm[4], ll[4], ww[4];
#pragma unroll
  for (int c = 0; c < 4; ++c) {
    const int j = jb * 4 + c;
    const float m0 = (j < k0) ? Wmu[k0 * D + j] : 0.f;
    const float m1 = (j < k1) ? Wmu[k1 * D + j] : 0.f;
    const float s0 = (j < k0) ? Wls[k0 * D + j] * LOG2E : 0.f;
    const float s1 = (j < k1) ? Wls[k1 * D + j] * LOG2E : 0.f;
    const float w0 = (j < k0) ? W1[k0 * D + j] : 0.f;
    const float w1_ = (j < k1) ? W1[k1 * D + j] : 0.f;
    mm[c] = pkbf(m0, m1);
    ll[c] = pkbf(s0, s1);
    ww[c] = pkbf(w0, w1_);
  }
  uint4 m4, l4, w4;
  m4.x = mm[0]; m4.y = mm[1]; m4.z = mm[2]; m4.w = mm[3];
  l4.x = ll[0]; l4.y = ll[1]; l4.z = ll[2]; l4.w = ll[3];
  w4.x = ww[0]; w4.y = ww[1]; w4.z = ww[2]; w4.w = ww[3];
  ws[t] = m4;
  ws[2048 + t] = l4;
  ws[4096 + t] = w4;
}

// ===== main: column sweep, 1 row/wave (32 waves/CU), minimal step, A/B sets =====
#define SEL(U, c) ((c) == 0 ? (U).x : (c) == 1 ? (U).y : (c) == 2 ? (U).z : (U).w)
#define E(V, c) (((c) & 1) ? (V).y : (V).x)

#define STEP(c, M4, L4, W4, JB)                                     \
  {                                                                 \
    const int Ln = (JB) * 2 + ((c) >> 1);                           \
    const f2 wm = unpkbf(SEL(M4, c));                               \
    const f2 wl = unpkbf(SEL(L4, c));                               \
    const f2 wv = unpkbf(SEL(W4, c));                               \
    const float h = fmaxf(E(pa, c), 0.f);                           \
    const float z = fmaf(E(xR, c), exp2x(E(pls, c)), E(pmu, c));    \
    const float sz = rdlane(z, Ln);                                 \
    const float sh = rdlane(h, Ln);                                 \
    pa = __builtin_elementwise_fma((f2)sz, wv, pa);                 \
    pmu = __builtin_elementwise_fma((f2)sh, wm, pmu);               \
    pls = __builtin_elementwise_fma((f2)sh, wl, pls);               \
  }

__global__ __launch_bounds__(1024, 8)
void iaf_main(const float* __restrict__ x, const float* __restrict__ b1,
              const float* __restrict__ bmu, const float* __restrict__ bls,
              const uint4* __restrict__ ws, float* __restrict__ out, int B) {
  __shared__ uint4 wsh[2 * 2048];  // 64KB: wmu4 | wls4 (W1 stays global/L2)

  const int tid = threadIdx.x;
#pragma unroll
  for (int k = 0; k < 4; ++k) wsh[tid + k * 1024] = ws[tid + k * 1024];

  const int lane = tid & 63;
  const int wave = tid >> 6;
  const int row = blockIdx.x * 16 + wave;  // 1 row per wave
  const int l2 = lane * 2;

  const f2 xR = *(const f2*)(x + (size_t)row * D + l2);
  f2 pa = *(const f2*)(b1 + l2);
  f2 pmu = *(const f2*)(bmu + l2);  // bias folded into init
  f2 pls = *(const f2*)(bls + l2);
  pls.x *= LOG2E;
  pls.y *= LOG2E;

  const uint4* wmuP = wsh + lane;
  const uint4* wlsP = wsh + 2048 + lane;
  const uint4* w1P = ws + 4096 + lane;  // W1 from global (L1/L2-shared)

  __syncthreads();

  uint4 m0 = wmuP[0], l0 = wlsP[0], w0 = w1P[0];

#pragma unroll 1
  for (int jb = 0; jb < 32; jb += 2) {
    // set 1 = block jb+1 (loaded a full half-iteration ahead of use)
    const uint4 m1 = wmuP[64];
    const uint4 l1 = wlsP[64];
    const uint4 w1v = w1P[64];
    STEP(0, m0, l0, w0, jb)
    STEP(1, m0, l0, w0, jb)
    STEP(2, m0, l0, w0, jb)
    STEP(3, m0, l0, w0, jb)
    const int adv = (jb + 2 < 32) ? 128 : 0;
    wmuP += adv;
    wlsP += adv;
    w1P += adv;
    m0 = wmuP[0];  // block jb+2 (redundant reload at tail; unused)
    l0 = wlsP[0];
    w0 = w1P[0];
    STEP(0, m1, l1, w1v, jb + 1)
    STEP(1, m1, l1, w1v, jb + 1)
    STEP(2, m1, l1, w1v, jb + 1)
    STEP(3, m1, l1, w1v, jb + 1)
  }

  // ---- outputs from frozen accumulators ----
  f2 zf;
  zf.x = fmaf(xR.x, exp2x(pls.x), pmu.x);
  zf.y = fmaf(xR.y, exp2x(pls.y), pmu.y);
  *(f2*)(out + (size_t)row * D + l2) = zf;

  float ldj = pls.x + pls.y;  // log2e-scaled; fix at the end
#pragma unroll
  for (int m2 = 1; m2 < 64; m2 <<= 1) ldj += __shfl_xor(ldj, m2);
  if (lane == 0) out[(size_t)B * D + row] = ldj * LN2;
}

// ================= fallback (proven R3 kernel, if ws too small) =================
#define FNTHR 256
#define FRPB 16
#define W1S 136
template <int CTRL>
__device__ __forceinline__ float dppmov(float v) {
  return __int_as_float(
      __builtin_amdgcn_update_dpp(0, __float_as_int(v), CTRL, 0xf, 0xf, true));
}
#define DPP_ADD(v, ctrl) (v) += dppmov<(ctrl)>((v))
__device__ __forceinline__ f2 unpk(uint32_t u) {
  f2 r;
  r.x = __uint_as_float(u << 16);
  r.y = __uint_as_float(u & 0xffff0000u);
  return r;
}
#define RED16F(v)      \
  do {                 \
    DPP_ADD(v, 0xB1);  \
    DPP_ADD(v, 0x4E);  \
    DPP_ADD(v, 0x124); \
    DPP_ADD(v, 0x128); \
  } while (0)
#define FSTEP(I, XE, ZRE, MKE, WM0, WM1, WL0, WL1)                  \
  {                                                                 \
    const float bmu_i = bmu[(I)];                                   \
    const float bls_i = bls[(I)];                                   \
    const f2 h0 = __builtin_elementwise_max(A0, (f2)0.f);           \
    const f2 h1 = __builtin_elementwise_max(A1, (f2)0.f);           \
    const f2 h2_ = __builtin_elementwise_max(A2, (f2)0.f);          \
    const f2 h3 = __builtin_elementwise_max(A3, (f2)0.f);           \
    const f2 q0 = h0 * mk0, q1 = h1 * mk1;                          \
    const f2 q2 = h2_ * mk2, q3 = h3 * mk3;                         \
    f2 am = q0 * WM0.xy;                                            \
    f2 al = q0 * WL0.xy;                                            \
    am = __builtin_elementwise_fma(q1, WM0.zw, am);                 \
    al = __builtin_elementwise_fma(q1, WL0.zw, al);                 \
    am = __builtin_elementwise_fma(q2, WM1.xy, am);                 \
    al = __builtin_elementwise_fma(q2, WL1.xy, al);                 \
    am = __builtin_elementwise_fma(q3, WM1.zw, am);                 \
    al = __builtin_elementwise_fma(q3, WL1.zw, al);                 \
    float mu_p = am.x + am.y;                                       \
    float ls_p = al.x + al.y;                                       \
    {                                                               \
      const int pfr = ((I) + 2 < D) ? (I) + 2 : D - 1;              \
      WM0 = *(const f4*)(wmup + pfr * D);                           \
      WM1 = *(const f4*)(wmup + pfr * D + 4);                       \
      WL0 = *(const f4*)(wlsp + pfr * D);                           \
      WL1 = *(const f4*)(wlsp + pfr * D + 4);                       \
    }                                                               \
    RED16F(mu_p);                                                   \
    RED16F(ls_p);                                                   \
    const float mu_t = mu_p + bmu_i;                                \
    const float ls_t = ls_p + bls_i;                                \
    const float zi = fmaf((XE), __expf(ls_t), mu_t);                \
    ldj += ls_t;                                                    \
    const uint4 wv = *(const uint4*)(w1p + (I)*W1S);                \
    if (own) {                                                      \
      ZRE = zi;                                                     \
      MKE = 1.f;                                                    \
    }                                                               \
    f2 zz;                                                          \
    zz.x = zi;                                                      \
    zz.y = zi;                                                      \
    A0 = __builtin_elementwise_fma(zz, unpk(wv.x), A0);             \
    A1 = __builtin_elementwise_fma(zz, unpk(wv.y), A1);             \
    A2 = __builtin_elementwise_fma(zz, unpk(wv.z), A2);             \
    A3 = __builtin_elementwise_fma(zz, unpk(wv.w), A3);             \
  }

__global__ __launch_bounds__(FNTHR, 2)
void iaf_fb(const float* __restrict__ x, const float* __restrict__ W1,
            const float* __restrict__ b1, const float* __restrict__ Wmu,
            const float* __restrict__ bmu, const float* __restrict__ Wls,
            const float* __restrict__ bls, float* __restrict__ out, int B) {
  __shared__ uint16_t w1c[D * W1S];
  const int tid = threadIdx.x;
  for (int idx = tid; idx < D * D; idx += FNTHR) {
    const int p = idx >> 7, q = idx & (D - 1);
    w1c[q * W1S + p] = f2bf((p > q) ? W1[idx] : 0.f);
  }
  __syncthreads();
  const int lane = tid & 63;
  const int m = lane & 15;
  const int row = blockIdx.x * FRPB + (tid >> 4);
  const float* __restrict__ xp = x + (size_t)row * D;
  const float* __restrict__ wmup = Wmu + m * 8;
  const float* __restrict__ wlsp = Wls + m * 8;
  const uint16_t* __restrict__ w1p = w1c + m * 8;
  f2 A0, A1, A2, A3;
  {
    const f4 t0 = *(const f4*)(b1 + m * 8);
    const f4 t1 = *(const f4*)(b1 + m * 8 + 4);
    A0 = t0.xy; A1 = t0.zw; A2 = t1.xy; A3 = t1.zw;
  }
  f2 mk0 = (f2)0.f, mk1 = (f2)0.f, mk2 = (f2)0.f, mk3 = (f2)0.f;
  float zr0 = 0, zr1 = 0, zr2 = 0, zr3 = 0, zr4 = 0, zr5 = 0, zr6 = 0, zr7 = 0;
  float ldj = 0.f;
  f4 wmA0 = *(const f4*)(wmup);
  f4 wmA1 = *(const f4*)(wmup + 4);
  f4 wlA0 = *(const f4*)(wlsp);
  f4 wlA1 = *(const f4*)(wlsp + 4);
  f4 wmB0 = *(const f4*)(wmup + D);
  f4 wmB1 = *(const f4*)(wmup + D + 4);
  f4 wlB0 = *(const f4*)(wlsp + D);
  f4 wlB1 = *(const f4*)(wlsp + D + 4);
  f4 x4a = *(const f4*)(xp);
  f4 x4b;
  for (int ib = 0; ib < 16; ++ib) {
    const int i0 = ib * 8;
    const bool own = (m == ib);
    x4b = *(const f4*)(xp + i0 + 4);
    FSTEP(i0 + 0, x4a.x, zr0, mk0.x, wmA0, wmA1, wlA0, wlA1);
    FSTEP(i0 + 1, x4a.y, zr1, mk0.y, wmB0, wmB1, wlB0, wlB1);
    FSTEP(i0 + 2, x4a.z, zr2, mk1.x, wmA0, wmA1, wlA0, wlA1);
    FSTEP(i0 + 3, x4a.w, zr3, mk1.y, wmB0, wmB1, wlB0, wlB1);
    {
      const int nx = (i0 + 8 < D) ? i0 + 8 : D - 4;
      x4a = *(const f4*)(xp + nx);
    }
    FSTEP(i0 + 4, x4b.x, zr4, mk2.x, wmA0, wmA1, wlA0, wlA1);
    FSTEP(i0 + 5, x4b.y, zr5, mk2.y, wmB0, wmB1, wlB0, wlB1);
    FSTEP(i0 + 6, x4b.z, zr6, mk3.x, wmA0, wmA1, wlA0, wlA1);
    FSTEP(i0 + 7, x4b.w, zr7, mk3.y, wmB0, wmB1, wlB0, wlB1);
  }
  f4 o0, o1;
  o0.x = zr0; o0.y = zr1; o0.z = zr2; o0.w = zr3;
  o1.x = zr4; o1.y = zr5; o1.z = zr6; o1.w = zr7;
  float* zo = out + (size_t)row * D + m * 8;
  *(f4*)(zo) = o0;
  *(f4*)(zo + 4) = o1;
  if (m == 0) out[(size_t)B * D + row] = ldj;
}

extern "C" void kernel_launch(void* const* d_in, const int* in_sizes, int n_in,
                              void* d_out, int out_size, void* d_ws, size_t ws_size,
                              hipStream_t stream) {
  const float* x   = (const float*)d_in[0];
  const float* W1  = (const float*)d_in[1];
  const float* b1  = (const float*)d_in[2];
  const float* Wmu = (const float*)d_in[3];
  const float* bmu = (const float*)d_in[4];
  const float* Wls = (const float*)d_in[5];
  const float* bls = (const float*)d_in[6];
  float* out = (float*)d_out;

  const int B = in_sizes[0] / D;  // 8192

  if (ws_size >= WS_NEED) {
    iaf_prep<<<8, 256, 0, stream>>>(W1, Wmu, Wls, (uint4*)d_ws);
    const int grid = (B + 15) / 16;  // 512 blocks x 16 rows (1 row/wave)
    iaf_main<<<grid, 1024, 0, stream>>>(x, b1, bmu, bls, (const uint4*)d_ws, out, B);
  } else {
    const int grid = (B + FRPB - 1) / FRPB;  // 512
    iaf_fb<<<grid, FNTHR, 0, stream>>>(x, W1, b1, Wmu, bmu, Wls, bls, out, B);
  }
}

// Round 17
// 36.409 us; speedup vs baseline: 1.1836x; 1.1836x over previous
//
#include <hip/hip_runtime.h>
#include <stdint.h>

#define D 128
#define LOG2E 1.4426950408889634f
#define LN2 0.6931471805599453f

typedef float f2 __attribute__((ext_vector_type(2)));
typedef float f4 __attribute__((ext_vector_type(4)));

__device__ __forceinline__ uint16_t f2bf(float f) {
  uint32_t u = __float_as_uint(f);
  u += 0x7fffu + ((u >> 16) & 1u);  // RNE
  return (uint16_t)(u >> 16);
}
__device__ __forceinline__ uint32_t pkbf(float a, float b) {
  return (uint32_t)f2bf(a) | ((uint32_t)f2bf(b) << 16);
}
__device__ __forceinline__ f2 unpkbf(uint32_t u) {
  f2 r;
  r.x = __uint_as_float(u << 16);
  r.y = __uint_as_float(u & 0xffff0000u);
  return r;
}
__device__ __forceinline__ float rdlane(float v, int l) {
  return __int_as_float(__builtin_amdgcn_readlane(__float_as_int(v), l));
}
__device__ __forceinline__ float exp2x(float v) {
#if __has_builtin(__builtin_amdgcn_exp2f)
  return __builtin_amdgcn_exp2f(v);
#else
  return exp2f(v);
#endif
}

// ws layout: 3 tables of uint4[32*64] (32KB each): WMU4 | WLS4(x log2e) | W14.
// entry[jb*64+l].c = pack(bf16 M[2l][4jb+c], bf16 M[2l+1][4jb+c]), masked j<row.
#define WS_NEED (size_t)(3 * 2048 * 16)  // 98304

// ================= prep: mask + column-pack into ws =================
__global__ __launch_bounds__(256)
void iaf_prep(const float* __restrict__ W1, const float* __restrict__ Wmu,
              const float* __restrict__ Wls, uint4* __restrict__ ws) {
  const int t = blockIdx.x * 256 + threadIdx.x;
  if (t >= 32 * 64) return;
  const int jb = t >> 6, l = t & 63;
  const int k0 = 2 * l, k1 = 2 * l + 1;
  uint32_t mm[4], ll[4], ww[4];
#pragma unroll
  for (int c = 0; c < 4; ++c) {
    const int j = jb * 4 + c;
    const float m0 = (j < k0) ? Wmu[k0 * D + j] : 0.f;
    const float m1 = (j < k1) ? Wmu[k1 * D + j] : 0.f;
    const float s0 = (j < k0) ? Wls[k0 * D + j] * LOG2E : 0.f;
    const float s1 = (j < k1) ? Wls[k1 * D + j] * LOG2E : 0.f;
    const float w0 = (j < k0) ? W1[k0 * D + j] : 0.f;
    const float w1_ = (j < k1) ? W1[k1 * D + j] : 0.f;
    mm[c] = pkbf(m0, m1);
    ll[c] = pkbf(s0, s1);
    ww[c] = pkbf(w0, w1_);
  }
  uint4 m4, l4, w4;
  m4.x = mm[0]; m4.y = mm[1]; m4.z = mm[2]; m4.w = mm[3];
  l4.x = ll[0]; l4.y = ll[1]; l4.z = ll[2]; l4.w = ll[3];
  w4.x = ww[0]; w4.y = ww[1]; w4.z = ww[2]; w4.w = ww[3];
  ws[t] = m4;
  ws[2048 + t] = l4;
  ws[4096 + t] = w4;
}

// ===== main: column sweep, 8 rows/wave (8-way ILP), all-LDS, A/B reg sets =====
#define SEL(U, c) ((c) == 0 ? (U).x : (c) == 1 ? (U).y : (c) == 2 ? (U).z : (U).w)
#define E(V, c) (((c) & 1) ? (V).y : (V).x)

#define STEP8(c, M4, L4, W4, JB)                                          \
  {                                                                       \
    const int Ln = (JB) * 2 + ((c) >> 1);                                 \
    const f2 wm = unpkbf(SEL(M4, c));                                     \
    const f2 wl = unpkbf(SEL(L4, c));                                     \
    const f2 wv = unpkbf(SEL(W4, c));                                     \
    _Pragma("unroll") for (int r = 0; r < 8; ++r) {                       \
      const float h = fmaxf(E(pa[r], c), 0.f);                            \
      const float z = fmaf(E(xR[r], c), exp2x(E(pls[r], c)), E(pmu[r], c)); \
      const float sz = rdlane(z, Ln);                                     \
      const float sh = rdlane(h, Ln);                                     \
      pa[r] = __builtin_elementwise_fma((f2)sz, wv, pa[r]);               \
      pmu[r] = __builtin_elementwise_fma((f2)sh, wm, pmu[r]);             \
      pls[r] = __builtin_elementwise_fma((f2)sh, wl, pls[r]);             \
    }                                                                     \
  }

__global__ __launch_bounds__(256, 1)
void iaf_main(const float* __restrict__ x, const float* __restrict__ b1,
              const float* __restrict__ bmu, const float* __restrict__ bls,
              const uint4* __restrict__ ws, float* __restrict__ out, int B) {
  __shared__ uint4 wsh[3 * 2048];  // 96KB: wmu4 | wls4 | w14

  const int tid = threadIdx.x;
#pragma unroll
  for (int k = 0; k < 24; ++k) wsh[tid + k * 256] = ws[tid + k * 256];

  const int lane = tid & 63;
  const int wave = tid >> 6;                    // 0..3
  const int r0 = blockIdx.x * 32 + wave * 8;    // 8 rows per wave
  const int l2 = lane * 2;

  f2 xR[8], pa[8], pmu[8], pls[8];
  {
    const f2 b1v = *(const f2*)(b1 + l2);
    const f2 bmv = *(const f2*)(bmu + l2);
    f2 blv = *(const f2*)(bls + l2);
    blv.x *= LOG2E;
    blv.y *= LOG2E;
#pragma unroll
    for (int r = 0; r < 8; ++r) {
      xR[r] = *(const f2*)(x + (size_t)(r0 + r) * D + l2);
      pa[r] = b1v;
      pmu[r] = bmv;  // biases folded into init
      pls[r] = blv;
    }
  }

  const uint4* wmuP = wsh + lane;
  const uint4* wlsP = wsh + 2048 + lane;
  const uint4* w1P = wsh + 4096 + lane;

  __syncthreads();

  uint4 m0 = wmuP[0], l0 = wlsP[0], w0 = w1P[0];

#pragma unroll 1
  for (int jb = 0; jb < 32; jb += 2) {
    // set 1 = block jb+1 (loaded a half-iteration ahead of use)
    const uint4 m1 = wmuP[64];
    const uint4 l1 = wlsP[64];
    const uint4 w1v = w1P[64];
    STEP8(0, m0, l0, w0, jb)
    STEP8(1, m0, l0, w0, jb)
    STEP8(2, m0, l0, w0, jb)
    STEP8(3, m0, l0, w0, jb)
    const int adv = (jb + 2 < 32) ? 128 : 0;
    wmuP += adv;
    wlsP += adv;
    w1P += adv;
    m0 = wmuP[0];  // block jb+2 (redundant tail reload; unused then)
    l0 = wlsP[0];
    w0 = w1P[0];
    STEP8(0, m1, l1, w1v, jb + 1)
    STEP8(1, m1, l1, w1v, jb + 1)
    STEP8(2, m1, l1, w1v, jb + 1)
    STEP8(3, m1, l1, w1v, jb + 1)
  }

  // ---- outputs from frozen accumulators ----
#pragma unroll
  for (int r = 0; r < 8; ++r) {
    f2 zf;
    zf.x = fmaf(xR[r].x, exp2x(pls[r].x), pmu[r].x);
    zf.y = fmaf(xR[r].y, exp2x(pls[r].y), pmu[r].y);
    *(f2*)(out + (size_t)(r0 + r) * D + l2) = zf;
  }
  float ldj[8];
#pragma unroll
  for (int r = 0; r < 8; ++r) ldj[r] = pls[r].x + pls[r].y;
#pragma unroll
  for (int m2 = 1; m2 < 64; m2 <<= 1) {
#pragma unroll
    for (int r = 0; r < 8; ++r) ldj[r] += __shfl_xor(ldj[r], m2);
  }
  if (lane == 0) {
#pragma unroll
    for (int r = 0; r < 8; ++r) out[(size_t)B * D + r0 + r] = ldj[r] * LN2;
  }
}

// ================= fallback (proven R3 kernel, if ws too small) =================
#define FNTHR 256
#define FRPB 16
#define W1S 136
template <int CTRL>
__device__ __forceinline__ float dppmov(float v) {
  return __int_as_float(
      __builtin_amdgcn_update_dpp(0, __float_as_int(v), CTRL, 0xf, 0xf, true));
}
#define DPP_ADD(v, ctrl) (v) += dppmov<(ctrl)>((v))
__device__ __forceinline__ f2 unpk(uint32_t u) {
  f2 r;
  r.x = __uint_as_float(u << 16);
  r.y = __uint_as_float(u & 0xffff0000u);
  return r;
}
#define RED16F(v)      \
  do {                 \
    DPP_ADD(v, 0xB1);  \
    DPP_ADD(v, 0x4E);  \
    DPP_ADD(v, 0x124); \
    DPP_ADD(v, 0x128); \
  } while (0)
#define FSTEP(I, XE, ZRE, MKE, WM0, WM1, WL0, WL1)                  \
  {                                                                 \
    const float bmu_i = bmu[(I)];                                   \
    const float bls_i = bls[(I)];                                   \
    const f2 h0 = __builtin_elementwise_max(A0, (f2)0.f);           \
    const f2 h1 = __builtin_elementwise_max(A1, (f2)0.f);           \
    const f2 h2_ = __builtin_elementwise_max(A2, (f2)0.f);          \
    const f2 h3 = __builtin_elementwise_max(A3, (f2)0.f);           \
    const f2 q0 = h0 * mk0, q1 = h1 * mk1;                          \
    const f2 q2 = h2_ * mk2, q3 = h3 * mk3;                         \
    f2 am = q0 * WM0.xy;                                            \
    f2 al = q0 * WL0.xy;                                            \
    am = __builtin_elementwise_fma(q1, WM0.zw, am);                 \
    al = __builtin_elementwise_fma(q1, WL0.zw, al);                 \
    am = __builtin_elementwise_fma(q2, WM1.xy, am);                 \
    al = __builtin_elementwise_fma(q2, WL1.xy, al);                 \
    am = __builtin_elementwise_fma(q3, WM1.zw, am);                 \
    al = __builtin_elementwise_fma(q3, WL1.zw, al);                 \
    float mu_p = am.x + am.y;                                       \
    float ls_p = al.x + al.y;                                       \
    {                                                               \
      const int pfr = ((I) + 2 < D) ? (I) + 2 : D - 1;              \
      WM0 = *(const f4*)(wmup + pfr * D);                           \
      WM1 = *(const f4*)(wmup + pfr * D + 4);                       \
      WL0 = *(const f4*)(wlsp + pfr * D);                           \
      WL1 = *(const f4*)(wlsp + pfr * D + 4);                       \
    }                                                               \
    RED16F(mu_p);                                                   \
    RED16F(ls_p);                                                   \
    const float mu_t = mu_p + bmu_i;                                \
    const float ls_t = ls_p + bls_i;                                \
    const float zi = fmaf((XE), __expf(ls_t), mu_t);                \
    ldj += ls_t;                                                    \
    const uint4 wv = *(const uint4*)(w1p + (I)*W1S);                \
    if (own) {                                                      \
      ZRE = zi;                                                     \
      MKE = 1.f;                                                    \
    }                                                               \
    f2 zz;                                                          \
    zz.x = zi;                                                      \
    zz.y = zi;                                                      \
    A0 = __builtin_elementwise_fma(zz, unpk(wv.x), A0);             \
    A1 = __builtin_elementwise_fma(zz, unpk(wv.y), A1);             \
    A2 = __builtin_elementwise_fma(zz, unpk(wv.z), A2);             \
    A3 = __builtin_elementwise_fma(zz, unpk(wv.w), A3);             \
  }

__global__ __launch_bounds__(FNTHR, 2)
void iaf_fb(const float* __restrict__ x, const float* __restrict__ W1,
            const float* __restrict__ b1, const float* __restrict__ Wmu,
            const float* __restrict__ bmu, const float* __restrict__ Wls,
            const float* __restrict__ bls, float* __restrict__ out, int B) {
  __shared__ uint16_t w1c[D * W1S];
  const int tid = threadIdx.x;
  for (int idx = tid; idx < D * D; idx += FNTHR) {
    const int p = idx >> 7, q = idx & (D - 1);
    w1c[q * W1S + p] = f2bf((p > q) ? W1[idx] : 0.f);
  }
  __syncthreads();
  const int lane = tid & 63;
  const int m = lane & 15;
  const int row = blockIdx.x * FRPB + (tid >> 4);
  const float* __restrict__ xp = x + (size_t)row * D;
  const float* __restrict__ wmup = Wmu + m * 8;
  const float* __restrict__ wlsp = Wls + m * 8;
  const uint16_t* __restrict__ w1p = w1c + m * 8;
  f2 A0, A1, A2, A3;
  {
    const f4 t0 = *(const f4*)(b1 + m * 8);
    const f4 t1 = *(const f4*)(b1 + m * 8 + 4);
    A0 = t0.xy; A1 = t0.zw; A2 = t1.xy; A3 = t1.zw;
  }
  f2 mk0 = (f2)0.f, mk1 = (f2)0.f, mk2 = (f2)0.f, mk3 = (f2)0.f;
  float zr0 = 0, zr1 = 0, zr2 = 0, zr3 = 0, zr4 = 0, zr5 = 0, zr6 = 0, zr7 = 0;
  float ldj = 0.f;
  f4 wmA0 = *(const f4*)(wmup);
  f4 wmA1 = *(const f4*)(wmup + 4);
  f4 wlA0 = *(const f4*)(wlsp);
  f4 wlA1 = *(const f4*)(wlsp + 4);
  f4 wmB0 = *(const f4*)(wmup + D);
  f4 wmB1 = *(const f4*)(wmup + D + 4);
  f4 wlB0 = *(const f4*)(wlsp + D);
  f4 wlB1 = *(const f4*)(wlsp + D + 4);
  f4 x4a = *(const f4*)(xp);
  f4 x4b;
  for (int ib = 0; ib < 16; ++ib) {
    const int i0 = ib * 8;
    const bool own = (m == ib);
    x4b = *(const f4*)(xp + i0 + 4);
    FSTEP(i0 + 0, x4a.x, zr0, mk0.x, wmA0, wmA1, wlA0, wlA1);
    FSTEP(i0 + 1, x4a.y, zr1, mk0.y, wmB0, wmB1, wlB0, wlB1);
    FSTEP(i0 + 2, x4a.z, zr2, mk1.x, wmA0, wmA1, wlA0, wlA1);
    FSTEP(i0 + 3, x4a.w, zr3, mk1.y, wmB0, wmB1, wlB0, wlB1);
    {
      const int nx = (i0 + 8 < D) ? i0 + 8 : D - 4;
      x4a = *(const f4*)(xp + nx);
    }
    FSTEP(i0 + 4, x4b.x, zr4, mk2.x, wmA0, wmA1, wlA0, wlA1);
    FSTEP(i0 + 5, x4b.y, zr5, mk2.y, wmB0, wmB1, wlB0, wlB1);
    FSTEP(i0 + 6, x4b.z, zr6, mk3.x, wmA0, wmA1, wlA0, wlA1);
    FSTEP(i0 + 7, x4b.w, zr7, mk3.y, wmB0, wmB1, wlB0, wlB1);
  }
  f4 o0, o1;
  o0.x = zr0; o0.y = zr1; o0.z = zr2; o0.w = zr3;
  o1.x = zr4; o1.y = zr5; o1.z = zr6; o1.w = zr7;
  float* zo = out + (size_t)row * D + m * 8;
  *(f4*)(zo) = o0;
  *(f4*)(zo + 4) = o1;
  if (m == 0) out[(size_t)B * D + row] = ldj;
}

extern "C" void kernel_launch(void* const* d_in, const int* in_sizes, int n_in,
                              void* d_out, int out_size, void* d_ws, size_t ws_size,
                              hipStream_t stream) {
  const float* x   = (const float*)d_in[0];
  const float* W1  = (const float*)d_in[1];
  const float* b1  = (const float*)d_in[2];
  const float* Wmu = (const float*)d_in[3];
  const float* bmu = (const float*)d_in[4];
  const float* Wls = (const float*)d_in[5];
  const float* bls = (const float*)d_in[6];
  float* out = (float*)d_out;

  const int B = in_sizes[0] / D;  // 8192

  if (ws_size >= WS_NEED) {
    iaf_prep<<<8, 256, 0, stream>>>(W1, Wmu, Wls, (uint4*)d_ws);
    const int grid = (B + 31) / 32;  // 256 blocks x 32 rows (8 rows/wave)
    iaf_main<<<grid, 256, 0, stream>>>(x, b1, bmu, bls, (const uint4*)d_ws, out, B);
  } else {
    const int grid = (B + FRPB - 1) / FRPB;  // 512
    iaf_fb<<<grid, FNTHR, 0, stream>>>(x, W1, b1, Wmu, bmu, Wls, bls, out, B);
  }
}

// Round 18
// 36.263 us; speedup vs baseline: 1.1884x; 1.0040x over previous
//
#include <hip/hip_runtime.h>
#include <stdint.h>

#define D 128
#define LOG2E 1.4426950408889634f
#define LN2 0.6931471805599453f

typedef float f2 __attribute__((ext_vector_type(2)));
typedef float f4 __attribute__((ext_vector_type(4)));

__device__ __forceinline__ uint16_t f2bf(float f) {
  uint32_t u = __float_as_uint(f);
  u += 0x7fffu + ((u >> 16) & 1u);  // RNE
  return (uint16_t)(u >> 16);
}
__device__ __forceinline__ uint32_t pkbf(float a, float b) {
  return (uint32_t)f2bf(a) | ((uint32_t)f2bf(b) << 16);
}
__device__ __forceinline__ f2 unpkbf(uint32_t u) {
  f2 r;
  r.x = __uint_as_float(u << 16);
  r.y = __uint_as_float(u & 0xffff0000u);
  return r;
}
__device__ __forceinline__ float rdlane(float v, int l) {
  return __int_as_float(__builtin_amdgcn_readlane(__float_as_int(v), l));
}
__device__ __forceinline__ float exp2x(float v) {
#if __has_builtin(__builtin_amdgcn_exp2f)
  return __builtin_amdgcn_exp2f(v);
#else
  return exp2f(v);
#endif
}

// ws layout: 3 tables of uint4[32*64] (32KB each): WMU4 | WLS4(x log2e) | W14.
// entry[jb*64+l].c = pack(bf16 M[2l][4jb+c], bf16 M[2l+1][4jb+c]), masked j<row.
#define WS_NEED (size_t)(3 * 2048 * 16)  // 98304

// ================= prep: mask + column-pack into ws =================
__global__ __launch_bounds__(256)
void iaf_prep(const float* __restrict__ W1, const float* __restrict__ Wmu,
              const float* __restrict__ Wls, uint4* __restrict__ ws) {
  const int t = blockIdx.x * 256 + threadIdx.x;
  if (t >= 32 * 64) return;
  const int jb = t >> 6, l = t & 63;
  const int k0 = 2 * l, k1 = 2 * l + 1;
  uint32_t mm[4], ll[4], ww[4];
#pragma unroll
  for (int c = 0; c < 4; ++c) {
    const int j = jb * 4 + c;
    const float m0 = (j < k0) ? Wmu[k0 * D + j] : 0.f;
    const float m1 = (j < k1) ? Wmu[k1 * D + j] : 0.f;
    const float s0 = (j < k0) ? Wls[k0 * D + j] * LOG2E : 0.f;
    const float s1 = (j < k1) ? Wls[k1 * D + j] * LOG2E : 0.f;
    const float w0 = (j < k0) ? W1[k0 * D + j] : 0.f;
    const float w1_ = (j < k1) ? W1[k1 * D + j] : 0.f;
    mm[c] = pkbf(m0, m1);
    ll[c] = pkbf(s0, s1);
    ww[c] = pkbf(w0, w1_);
  }
  uint4 m4, l4, w4;
  m4.x = mm[0]; m4.y = mm[1]; m4.z = mm[2]; m4.w = mm[3];
  l4.x = ll[0]; l4.y = ll[1]; l4.z = ll[2]; l4.w = ll[3];
  w4.x = ww[0]; w4.y = ww[1]; w4.z = ww[2]; w4.w = ww[3];
  ws[t] = m4;
  ws[2048 + t] = l4;
  ws[4096 + t] = w4;
}

// ===== main: column sweep, 8 rows/wave, STAGE-PARALLEL step (chains interleaved) =====
#define SEL(U, c) ((c) == 0 ? (U).x : (c) == 1 ? (U).y : (c) == 2 ? (U).z : (U).w)
#define E(V, c) (((c) & 1) ? (V).y : (V).x)

#define STEP8(c, M4, L4, W4, JB)                                            \
  {                                                                         \
    const int Ln = (JB) * 2 + ((c) >> 1);                                   \
    const f2 wm = unpkbf(SEL(M4, c));                                       \
    const f2 wl = unpkbf(SEL(L4, c));                                       \
    const f2 wv = unpkbf(SEL(W4, c));                                       \
    float h_[8], e_[8], z_[8], sz_[8], sh_[8];                              \
    _Pragma("unroll") for (int r = 0; r < 8; ++r)                           \
        h_[r] = fmaxf(E(pa[r], c), 0.f);                                    \
    _Pragma("unroll") for (int r = 0; r < 8; ++r)                           \
        e_[r] = exp2x(E(pls[r], c));                                        \
    _Pragma("unroll") for (int r = 0; r < 8; ++r)                           \
        z_[r] = fmaf(E(xR[r], c), e_[r], E(pmu[r], c));                     \
    _Pragma("unroll") for (int r = 0; r < 8; ++r) {                         \
      sz_[r] = rdlane(z_[r], Ln);                                           \
      sh_[r] = rdlane(h_[r], Ln);                                           \
    }                                                                       \
    _Pragma("unroll") for (int r = 0; r < 8; ++r) {                         \
      pa[r] = __builtin_elementwise_fma((f2)sz_[r], wv, pa[r]);             \
      pmu[r] = __builtin_elementwise_fma((f2)sh_[r], wm, pmu[r]);           \
      pls[r] = __builtin_elementwise_fma((f2)sh_[r], wl, pls[r]);           \
    }                                                                       \
  }

__global__ __launch_bounds__(256, 1)
void iaf_main(const float* __restrict__ x, const float* __restrict__ b1,
              const float* __restrict__ bmu, const float* __restrict__ bls,
              const uint4* __restrict__ ws, float* __restrict__ out, int B) {
  __shared__ uint4 wsh[3 * 2048];  // 96KB: wmu4 | wls4 | w14

  const int tid = threadIdx.x;
#pragma unroll
  for (int k = 0; k < 24; ++k) wsh[tid + k * 256] = ws[tid + k * 256];

  const int lane = tid & 63;
  const int wave = tid >> 6;                  // 0..3
  const int r0 = blockIdx.x * 32 + wave * 8;  // 8 rows per wave
  const int l2 = lane * 2;

  f2 xR[8], pa[8], pmu[8], pls[8];
  {
    const f2 b1v = *(const f2*)(b1 + l2);
    const f2 bmv = *(const f2*)(bmu + l2);
    f2 blv = *(const f2*)(bls + l2);
    blv.x *= LOG2E;
    blv.y *= LOG2E;
#pragma unroll
    for (int r = 0; r < 8; ++r) {
      xR[r] = *(const f2*)(x + (size_t)(r0 + r) * D + l2);
      pa[r] = b1v;
      pmu[r] = bmv;  // biases folded into init
      pls[r] = blv;
    }
  }

  const uint4* wmuP = wsh + lane;
  const uint4* wlsP = wsh + 2048 + lane;
  const uint4* w1P = wsh + 4096 + lane;

  __syncthreads();

  uint4 m0 = wmuP[0], l0 = wlsP[0], w0 = w1P[0];

#pragma unroll 1
  for (int jb = 0; jb < 32; jb += 2) {
    // set 1 = block jb+1 (loaded a half-iteration ahead of use)
    const uint4 m1 = wmuP[64];
    const uint4 l1 = wlsP[64];
    const uint4 w1v = w1P[64];
    STEP8(0, m0, l0, w0, jb)
    STEP8(1, m0, l0, w0, jb)
    STEP8(2, m0, l0, w0, jb)
    STEP8(3, m0, l0, w0, jb)
    const int adv = (jb + 2 < 32) ? 128 : 0;
    wmuP += adv;
    wlsP += adv;
    w1P += adv;
    m0 = wmuP[0];  // block jb+2 (redundant tail reload; unused then)
    l0 = wlsP[0];
    w0 = w1P[0];
    STEP8(0, m1, l1, w1v, jb + 1)
    STEP8(1, m1, l1, w1v, jb + 1)
    STEP8(2, m1, l1, w1v, jb + 1)
    STEP8(3, m1, l1, w1v, jb + 1)
  }

  // ---- outputs from frozen accumulators ----
#pragma unroll
  for (int r = 0; r < 8; ++r) {
    f2 zf;
    zf.x = fmaf(xR[r].x, exp2x(pls[r].x), pmu[r].x);
    zf.y = fmaf(xR[r].y, exp2x(pls[r].y), pmu[r].y);
    *(f2*)(out + (size_t)(r0 + r) * D + l2) = zf;
  }
  float ldj[8];
#pragma unroll
  for (int r = 0; r < 8; ++r) ldj[r] = pls[r].x + pls[r].y;
#pragma unroll
  for (int m2 = 1; m2 < 64; m2 <<= 1) {
#pragma unroll
    for (int r = 0; r < 8; ++r) ldj[r] += __shfl_xor(ldj[r], m2);
  }
  if (lane == 0) {
#pragma unroll
    for (int r = 0; r < 8; ++r) out[(size_t)B * D + r0 + r] = ldj[r] * LN2;
  }
}

// ================= fallback (proven R3 kernel, if ws too small) =================
#define FNTHR 256
#define FRPB 16
#define W1S 136
template <int CTRL>
__device__ __forceinline__ float dppmov(float v) {
  return __int_as_float(
      __builtin_amdgcn_update_dpp(0, __float_as_int(v), CTRL, 0xf, 0xf, true));
}
#define DPP_ADD(v, ctrl) (v) += dppmov<(ctrl)>((v))
__device__ __forceinline__ f2 unpk(uint32_t u) {
  f2 r;
  r.x = __uint_as_float(u << 16);
  r.y = __uint_as_float(u & 0xffff0000u);
  return r;
}
#define RED16F(v)      \
  do {                 \
    DPP_ADD(v, 0xB1);  \
    DPP_ADD(v, 0x4E);  \
    DPP_ADD(v, 0x124); \
    DPP_ADD(v, 0x128); \
  } while (0)
#define FSTEP(I, XE, ZRE, MKE, WM0, WM1, WL0, WL1)                  \
  {                                                                 \
    const float bmu_i = bmu[(I)];                                   \
    const float bls_i = bls[(I)];                                   \
    const f2 h0 = __builtin_elementwise_max(A0, (f2)0.f);           \
    const f2 h1 = __builtin_elementwise_max(A1, (f2)0.f);           \
    const f2 h2_ = __builtin_elementwise_max(A2, (f2)0.f);          \
    const f2 h3 = __builtin_elementwise_max(A3, (f2)0.f);           \
    const f2 q0 = h0 * mk0, q1 = h1 * mk1;                          \
    const f2 q2 = h2_ * mk2, q3 = h3 * mk3;                         \
    f2 am = q0 * WM0.xy;                                            \
    f2 al = q0 * WL0.xy;                                            \
    am = __builtin_elementwise_fma(q1, WM0.zw, am);                 \
    al = __builtin_elementwise_fma(q1, WL0.zw, al);                 \
    am = __builtin_elementwise_fma(q2, WM1.xy, am);                 \
    al = __builtin_elementwise_fma(q2, WL1.xy, al);                 \
    am = __builtin_elementwise_fma(q3, WM1.zw, am);                 \
    al = __builtin_elementwise_fma(q3, WL1.zw, al);                 \
    float mu_p = am.x + am.y;                                       \
    float ls_p = al.x + al.y;                                       \
    {                                                               \
      const int pfr = ((I) + 2 < D) ? (I) + 2 : D - 1;              \
      WM0 = *(const f4*)(wmup + pfr * D);                           \
      WM1 = *(const f4*)(wmup + pfr * D + 4);                       \
      WL0 = *(const f4*)(wlsp + pfr * D);                           \
      WL1 = *(const f4*)(wlsp + pfr * D + 4);                       \
    }                                                               \
    RED16F(mu_p);                                                   \
    RED16F(ls_p);                                                   \
    const float mu_t = mu_p + bmu_i;                                \
    const float ls_t = ls_p + bls_i;                                \
    const float zi = fmaf((XE), __expf(ls_t), mu_t);                \
    ldj += ls_t;                                                    \
    const uint4 wv = *(const uint4*)(w1p + (I)*W1S);                \
    if (own) {                                                      \
      ZRE = zi;                                                     \
      MKE = 1.f;                                                    \
    }                                                               \
    f2 zz;                                                          \
    zz.x = zi;                                                      \
    zz.y = zi;                                                      \
    A0 = __builtin_elementwise_fma(zz, unpk(wv.x), A0);             \
    A1 = __builtin_elementwise_fma(zz, unpk(wv.y), A1);             \
    A2 = __builtin_elementwise_fma(zz, unpk(wv.z), A2);             \
    A3 = __builtin_elementwise_fma(zz, unpk(wv.w), A3);             \
  }

__global__ __launch_bounds__(FNTHR, 2)
void iaf_fb(const float* __restrict__ x, const float* __restrict__ W1,
            const float* __restrict__ b1, const float* __restrict__ Wmu,
            const float* __restrict__ bmu, const float* __restrict__ Wls,
            const float* __restrict__ bls, float* __restrict__ out, int B) {
  __shared__ uint16_t w1c[D * W1S];
  const int tid = threadIdx.x;
  for (int idx = tid; idx < D * D; idx += FNTHR) {
    const int p = idx >> 7, q = idx & (D - 1);
    w1c[q * W1S + p] = f2bf((p > q) ? W1[idx] : 0.f);
  }
  __syncthreads();
  const int lane = tid & 63;
  const int m = lane & 15;
  const int row = blockIdx.x * FRPB + (tid >> 4);
  const float* __restrict__ xp = x + (size_t)row * D;
  const float* __restrict__ wmup = Wmu + m * 8;
  const float* __restrict__ wlsp = Wls + m * 8;
  const uint16_t* __restrict__ w1p = w1c + m * 8;
  f2 A0, A1, A2, A3;
  {
    const f4 t0 = *(const f4*)(b1 + m * 8);
    const f4 t1 = *(const f4*)(b1 + m * 8 + 4);
    A0 = t0.xy; A1 = t0.zw; A2 = t1.xy; A3 = t1.zw;
  }
  f2 mk0 = (f2)0.f, mk1 = (f2)0.f, mk2 = (f2)0.f, mk3 = (f2)0.f;
  float zr0 = 0, zr1 = 0, zr2 = 0, zr3 = 0, zr4 = 0, zr5 = 0, zr6 = 0, zr7 = 0;
  float ldj = 0.f;
  f4 wmA0 = *(const f4*)(wmup);
  f4 wmA1 = *(const f4*)(wmup + 4);
  f4 wlA0 = *(const f4*)(wlsp);
  f4 wlA1 = *(const f4*)(wlsp + 4);
  f4 wmB0 = *(const f4*)(wmup + D);
  f4 wmB1 = *(const f4*)(wmup + D + 4);
  f4 wlB0 = *(const f4*)(wlsp + D);
  f4 wlB1 = *(const f4*)(wlsp + D + 4);
  f4 x4a = *(const f4*)(xp);
  f4 x4b;
  for (int ib = 0; ib < 16; ++ib) {
    const int i0 = ib * 8;
    const bool own = (m == ib);
    x4b = *(const f4*)(xp + i0 + 4);
    FSTEP(i0 + 0, x4a.x, zr0, mk0.x, wmA0, wmA1, wlA0, wlA1);
    FSTEP(i0 + 1, x4a.y, zr1, mk0.y, wmB0, wmB1, wlB0, wlB1);
    FSTEP(i0 + 2, x4a.z, zr2, mk1.x, wmA0, wmA1, wlA0, wlA1);
    FSTEP(i0 + 3, x4a.w, zr3, mk1.y, wmB0, wmB1, wlB0, wlB1);
    {
      const int nx = (i0 + 8 < D) ? i0 + 8 : D - 4;
      x4a = *(const f4*)(xp + nx);
    }
    FSTEP(i0 + 4, x4b.x, zr4, mk2.x, wmA0, wmA1, wlA0, wlA1);
    FSTEP(i0 + 5, x4b.y, zr5, mk2.y, wmB0, wmB1, wlB0, wlB1);
    FSTEP(i0 + 6, x4b.z, zr6, mk3.x, wmA0, wmA1, wlA0, wlA1);
    FSTEP(i0 + 7, x4b.w, zr7, mk3.y, wmB0, wmB1, wlB0, wlB1);
  }
  f4 o0, o1;
  o0.x = zr0; o0.y = zr1; o0.z = zr2; o0.w = zr3;
  o1.x = zr4; o1.y = zr5; o1.z = zr6; o1.w = zr7;
  float* zo = out + (size_t)row * D + m * 8;
  *(f4*)(zo) = o0;
  *(f4*)(zo + 4) = o1;
  if (m == 0) out[(size_t)B * D + row] = ldj;
}

extern "C" void kernel_launch(void* const* d_in, const int* in_sizes, int n_in,
                              void* d_out, int out_size, void* d_ws, size_t ws_size,
                              hipStream_t stream) {
  const float* x   = (const float*)d_in[0];
  const float* W1  = (const float*)d_in[1];
  const float* b1  = (const float*)d_in[2];
  const float* Wmu = (const float*)d_in[3];
  const float* bmu = (const float*)d_in[4];
  const float* Wls = (const float*)d_in[5];
  const float* bls = (const float*)d_in[6];
  float* out = (float*)d_out;

  const int B = in_sizes[0] / D;  // 8192

  if (ws_size >= WS_NEED) {
    iaf_prep<<<8, 256, 0, stream>>>(W1, Wmu, Wls, (uint4*)d_ws);
    const int grid = (B + 31) / 32;  // 256 blocks x 32 rows (8 rows/wave)
    iaf_main<<<grid, 256, 0, stream>>>(x, b1, bmu, bls, (const uint4*)d_ws, out, B);
  } else {
    const int grid = (B + FRPB - 1) / FRPB;  // 512
    iaf_fb<<<grid, FNTHR, 0, stream>>>(x, W1, b1, Wmu, bmu, Wls, bls, out, B);
  }
}